// Round 2
// baseline (299.310 us; speedup 1.0000x reference)
//
#include <hip/hip_runtime.h>
#include <math.h>

#define D 128
#define H 8
#define C 16
#define NEG_SLOPE 0.2f
#define SCAN_TILE 1024  // elements per scan block (256 thr x 4)

// ---- bucket partition params (CSR build without global returning atomics) ----
#define BSHIFT 12
#define BRANGE 4096            // nodes per bucket (LDS counters = 16KB)
#define NBMAX 16               // compile-time max buckets (N <= 64K)
#define EPT 32                 // edges per thread in bucket pass
#define BEDGES (256 * EPT)     // 8192 edges per bucket block
#define CAP 98304              // per-bucket capacity (mean ~65.5K, ~130 sigma margin)
#define CSPLIT 4               // count blocks per bucket

typedef unsigned short ushortT;
typedef __attribute__((ext_vector_type(8))) short short8;
typedef __attribute__((ext_vector_type(4))) float f32x4;

// bf16 <-> f32 helpers (RNE pack; no NaN inputs here)
__device__ __forceinline__ float bf2f(unsigned short v) {
    union { unsigned int i; float f; } c;
    c.i = ((unsigned int)v) << 16;
    return c.f;
}
__device__ __forceinline__ unsigned short f2bf(float f) {
    union { float f; unsigned int i; } c;
    c.f = f;
    unsigned int lsb = (c.i >> 16) & 1u;
    c.i += 0x7fffu + lsb;
    return (unsigned short)(c.i >> 16);
}

// padded count per node = (cnt + 1 self-loop + 3) & ~3  (>= 4, multiple of 4)
__device__ __forceinline__ int padc(int c) { return (c + 4) & ~3; }

// A-frag address for element (row r, col k):
// wt=r>>4, m=r&15, kt=k>>5, quad=(k>>3)&3, j=k&7, lane=m+16*quad
// addr = ((wt*4+kt)*64 + lane)*8 + j     (2048 ushorts per 16x128 tile)

// ---------------- fused prep: bucket | wprep | xsplit (independent) --------------
// bucket: 2-pass register-counter partition by dst>>12. Ranks via wave shfl
// prefix + 16 returning atomics PER BLOCK (total ~1.6K, vs 800K per-edge).
// Edge packed as (local_dst<<17)|src in one int (local_dst<4096, src<131072).

__device__ __forceinline__ void bucket_part(
    int b, int t, const int* __restrict__ ei, int* __restrict__ bkt,
    int* __restrict__ bcur, int E) {
    __shared__ int wtot[4][NBMAX];
    __shared__ int wbase[4][NBMAX];
    int w = t >> 6, lane = t & 63;
    int base = b * BEDGES;

    int cnt[NBMAX];
#pragma unroll
    for (int q = 0; q < NBMAX; q++) cnt[q] = 0;

    // pass 1: count per bucket (compile-time-indexed register counters)
#pragma unroll
    for (int it = 0; it < EPT / 4; it++) {
        int idx = base + it * 1024 + t * 4;
        if (idx + 3 < E) {
            int4 dv = *(const int4*)(ei + (size_t)E + idx);
            int b0 = dv.x >> BSHIFT, b1 = dv.y >> BSHIFT;
            int b2 = dv.z >> BSHIFT, b3 = dv.w >> BSHIFT;
#pragma unroll
            for (int q = 0; q < NBMAX; q++)
                cnt[q] += (b0 == q) + (b1 == q) + (b2 == q) + (b3 == q);
        } else {
            for (int k = idx; k < E && k < idx + 4; k++) {
                int bq = ei[(size_t)E + k] >> BSHIFT;
#pragma unroll
                for (int q = 0; q < NBMAX; q++) cnt[q] += (bq == q);
            }
        }
    }

    // wave-level exclusive prefix per bucket
    int pre[NBMAX];
#pragma unroll
    for (int q = 0; q < NBMAX; q++) {
        int p = cnt[q];
#pragma unroll
        for (int o = 1; o < 64; o <<= 1) {
            int v = __shfl_up(p, o);
            if (lane >= o) p += v;
        }
        pre[q] = p - cnt[q];
        if (lane == 63) wtot[w][q] = p;
    }
    __syncthreads();
    if (t < NBMAX) {
        int q = t;
        int s0 = wtot[0][q], s1 = wtot[1][q], s2 = wtot[2][q], s3 = wtot[3][q];
        int tot = s0 + s1 + s2 + s3;
        int gb = (tot > 0) ? atomicAdd(bcur + q * 16, tot) : 0;
        wbase[0][q] = gb;
        wbase[1][q] = gb + s0;
        wbase[2][q] = gb + s0 + s1;
        wbase[3][q] = gb + s0 + s1 + s2;
    }
    __syncthreads();
    int cur[NBMAX];
#pragma unroll
    for (int q = 0; q < NBMAX; q++) cur[q] = wbase[w][q] + pre[q];

    // pass 2: place (one store per edge; cndmask select chain for the cursor)
#pragma unroll
    for (int it = 0; it < EPT / 4; it++) {
        int idx = base + it * 1024 + t * 4;
        if (idx + 3 < E) {
            int4 sv = *(const int4*)(ei + idx);
            int4 dv = *(const int4*)(ei + (size_t)E + idx);
            int dd[4] = {dv.x, dv.y, dv.z, dv.w};
            int ss[4] = {sv.x, sv.y, sv.z, sv.w};
#pragma unroll
            for (int e = 0; e < 4; e++) {
                int bq = dd[e] >> BSHIFT;
                int pk = ((dd[e] & (BRANGE - 1)) << 17) | ss[e];
                int off = cur[0];
#pragma unroll
                for (int q = 1; q < NBMAX; q++) off = (bq == q) ? cur[q] : off;
                if (off < CAP) bkt[(size_t)bq * CAP + off] = pk;
#pragma unroll
                for (int q = 0; q < NBMAX; q++) cur[q] += (bq == q);
            }
        } else {
            for (int k = idx; k < E && k < idx + 4; k++) {
                int d = ei[(size_t)E + k], s = ei[k];
                int bq = d >> BSHIFT;
                int pk = ((d & (BRANGE - 1)) << 17) | s;
                int off = cur[0];
#pragma unroll
                for (int q = 1; q < NBMAX; q++) off = (bq == q) ? cur[q] : off;
                if (off < CAP) bkt[(size_t)bq * CAP + off] = pk;
#pragma unroll
                for (int q = 0; q < NBMAX; q++) cur[q] += (bq == q);
            }
        }
    }
}

__device__ __forceinline__ void wprep_part(
    int b2, int t, const float* __restrict__ W1, const float* __restrict__ as1,
    const float* __restrict__ ad1, const float* __restrict__ W2,
    const float* __restrict__ as2, const float* __restrict__ ad2,
    ushortT* __restrict__ wf1_hi, ushortT* __restrict__ wf1_lo,
    ushortT* __restrict__ wf2_hi, ushortT* __restrict__ wf2_lo) {
    const float *W, *att_s, *att_d;
    ushortT *whi, *wlo;
    int idx;
    if (b2 < 9) {
        W = W1; att_s = as1; att_d = ad1; whi = wf1_hi; wlo = wf1_lo;
        idx = b2 * 256 + t;
    } else {
        W = W2; att_s = as2; att_d = ad2; whi = wf2_hi; wlo = wf2_lo;
        idx = (b2 - 9) * 256 + t;
    }
    if (idx >= 4 * 9 * 64) return;
    int lane = idx & 63;
    int nt = (idx >> 6) % 9;
    int kt = idx / (9 * 64);
    int quad = lane >> 4, ncol = lane & 15;
#pragma unroll
    for (int j = 0; j < 8; j++) {
        int k = kt * 32 + quad * 8 + j;
        float v;
        if (nt < 8) {
            v = W[k * D + nt * 16 + ncol];
        } else {
            const float* att = (ncol < 8) ? att_s : att_d;
            int hd = ncol & 7;
            float s = 0.f;
            for (int c = 0; c < 16; c++)
                s += W[k * D + hd * 16 + c] * att[hd * 16 + c];
            v = s;
        }
        unsigned short hi = f2bf(v);
        unsigned short lo = f2bf(v - bf2f(hi));
        whi[idx * 8 + j] = hi;
        wlo[idx * 8 + j] = lo;
    }
}

__device__ __forceinline__ void xsplit_part(
    int idx, const float* __restrict__ x, ushortT* __restrict__ xh,
    ushortT* __restrict__ xl, int n, int nt16) {
    int r = idx >> 4;
    if (r >= nt16 * 16) return;
    int kb = idx & 15;
    float4 v0 = make_float4(0.f, 0.f, 0.f, 0.f), v1 = v0;
    if (r < n) {
        v0 = ((const float4*)(x + (size_t)r * D + kb * 8))[0];
        v1 = ((const float4*)(x + (size_t)r * D + kb * 8))[1];
    }
    int wt = r >> 4, m = r & 15, kt = kb >> 2, quad = kb & 3;
    int base = ((wt * 4 + kt) * 64 + (m + 16 * quad)) * 8;
    ushort4 h0, l0, h1, l1;
    h0.x = f2bf(v0.x); l0.x = f2bf(v0.x - bf2f(h0.x));
    h0.y = f2bf(v0.y); l0.y = f2bf(v0.y - bf2f(h0.y));
    h0.z = f2bf(v0.z); l0.z = f2bf(v0.z - bf2f(h0.z));
    h0.w = f2bf(v0.w); l0.w = f2bf(v0.w - bf2f(h0.w));
    h1.x = f2bf(v1.x); l1.x = f2bf(v1.x - bf2f(h1.x));
    h1.y = f2bf(v1.y); l1.y = f2bf(v1.y - bf2f(h1.y));
    h1.z = f2bf(v1.z); l1.z = f2bf(v1.z - bf2f(h1.z));
    h1.w = f2bf(v1.w); l1.w = f2bf(v1.w - bf2f(h1.w));
    *(ushort4*)(xh + base) = h0;
    *(ushort4*)(xh + base + 4) = h1;
    *(ushort4*)(xl + base) = l0;
    *(ushort4*)(xl + base + 4) = l1;
}

__global__ __launch_bounds__(256) void k_prep(
    const int* __restrict__ ei, int* __restrict__ bkt, int* __restrict__ bcur,
    int E, const float* __restrict__ x, ushortT* __restrict__ xh,
    ushortT* __restrict__ xl, int n, int nt16,
    const float* __restrict__ W1, const float* __restrict__ as1,
    const float* __restrict__ ad1, const float* __restrict__ W2,
    const float* __restrict__ as2, const float* __restrict__ ad2,
    ushortT* __restrict__ wf1_hi, ushortT* __restrict__ wf1_lo,
    ushortT* __restrict__ wf2_hi, ushortT* __restrict__ wf2_lo, int nbb) {
    int b = blockIdx.x;
    int t = threadIdx.x;
    if (b < nbb) {
        bucket_part(b, t, ei, bkt, bcur, E);
    } else if (b < nbb + 18) {
        wprep_part(b - nbb, t, W1, as1, ad1, W2, as2, ad2,
                   wf1_hi, wf1_lo, wf2_hi, wf2_lo);
    } else {
        xsplit_part((b - nbb - 18) * 256 + t, x, xh, xl, n, nt16);
    }
}

// ---------------- per-bucket LDS histogram -> cursor (non-returning merge) ------

__global__ __launch_bounds__(256) void k_count(
    const int* __restrict__ bkt, const int* __restrict__ bcur,
    int* __restrict__ cursor, int n) {
    __shared__ int lcnt[BRANGE];
    int t = threadIdx.x;
    int q = blockIdx.x / CSPLIT, s = blockIdx.x % CSPLIT;
    for (int i = t; i < BRANGE; i += 256) lcnt[i] = 0;
    __syncthreads();
    int tot = bcur[q * 16];
    if (tot > CAP) tot = CAP;
    int per = ((tot + CSPLIT - 1) / CSPLIT + 3) & ~3;   // 4-aligned split
    int lo = s * per;
    int hi = lo + per; if (hi > tot) hi = tot;
    const int* bp = bkt + (size_t)q * CAP;
    for (int i = lo + t * 4; i < hi; i += 1024) {
        if (i + 3 < hi) {
            int4 v = *(const int4*)(bp + i);
            atomicAdd(&lcnt[v.x >> 17], 1);
            atomicAdd(&lcnt[v.y >> 17], 1);
            atomicAdd(&lcnt[v.z >> 17], 1);
            atomicAdd(&lcnt[v.w >> 17], 1);
        } else {
            for (int k = i; k < hi; k++) atomicAdd(&lcnt[bp[k] >> 17], 1);
        }
    }
    __syncthreads();
    int nb = q * BRANGE;
    for (int i = t; i < BRANGE; i += 256) {
        int node = nb + i;
        if (node < n) {
            int c = lcnt[i];
            if (c) atomicAdd(&cursor[node], c);   // non-returning, fire-and-forget
        }
    }
}

// ---------------- single-pass decoupled-lookback scan + self-loop/pads ----------
// <=64 blocks, all co-resident on 256 CUs -> spin-free-deadlock guaranteed.

__global__ __launch_bounds__(256) void k_scan_lb(
    const int* __restrict__ cursor, int* __restrict__ poffs,
    int* __restrict__ sstate, int* __restrict__ csrsrc, int n) {
    __shared__ int lds[256];
    __shared__ int bprefix;
    int t = threadIdx.x;
    int b = blockIdx.x;
    int base = b * SCAN_TILE + t * 4;
    int c[4] = {0, 0, 0, 0};
    if (base + 3 < n) {
        int4 q = *(const int4*)(cursor + base);
        c[0] = q.x; c[1] = q.y; c[2] = q.z; c[3] = q.w;
    } else {
        for (int k = 0; k < 4; k++)
            if (base + k < n) c[k] = cursor[base + k];
    }
    int s = padc(c[0]) + padc(c[1]) + padc(c[2]) + padc(c[3]);
    lds[t] = s;
    __syncthreads();
    for (int st = 1; st < 256; st <<= 1) {
        int add = (t >= st) ? lds[t - st] : 0;
        __syncthreads();
        lds[t] += add;
        __syncthreads();
    }
    if (t == 0)
        __hip_atomic_store(&sstate[b], lds[255] | (1 << 30),
                           __ATOMIC_RELEASE, __HIP_MEMORY_SCOPE_AGENT);
    if (t < 64) {
        int v = 0;
        if (t < b) {
            int x;
            do {
                x = __hip_atomic_load(&sstate[t], __ATOMIC_RELAXED,
                                      __HIP_MEMORY_SCOPE_AGENT);
            } while (!(x & (1 << 30)));
            v = x & 0x3FFFFFFF;
        }
#pragma unroll
        for (int o = 32; o > 0; o >>= 1) v += __shfl_down(v, o);
        if (t == 0) bprefix = v;
    }
    __syncthreads();
    int run = bprefix + ((t == 0) ? 0 : lds[t - 1]);
    if (b == 0 && t == 0) poffs[0] = 0;
#pragma unroll
    for (int k = 0; k < 4; k++) {
        int i = base + k;
        if (i < n) {
            int pv = padc(c[k]);
            csrsrc[run + c[k]] = i;                        // self-loop last
            for (int k2 = c[k] + 1; k2 < pv; k2++)
                csrsrc[run + k2] = n;                      // sentinel pads
            run += pv;
            poffs[i + 1] = run;
        }
    }
}

// ---------------- gemm wave body (split-bf16 MFMA, LDS-free) ----------------

__device__ __forceinline__ void gemm_wave(
    int wt, int lane, const ushortT* __restrict__ xh,
    const ushortT* __restrict__ xl, const ushortT* __restrict__ wf_hi,
    const ushortT* __restrict__ wf_lo, ushortT* __restrict__ hout,
    float* __restrict__ as_, float* __restrict__ ad_, int n) {
    f32x4 acc[9];
#pragma unroll
    for (int nt = 0; nt < 9; nt++) acc[nt] = (f32x4){0.f, 0.f, 0.f, 0.f};

#pragma unroll
    for (int kt = 0; kt < 4; kt++) {
        short8 a_hi = *(const short8*)(xh + (size_t)((wt * 4 + kt) * 64 + lane) * 8);
        short8 a_lo = *(const short8*)(xl + (size_t)((wt * 4 + kt) * 64 + lane) * 8);
        const ushortT* bh = wf_hi + (size_t)(kt * 576 + lane) * 8;
        const ushortT* bl = wf_lo + (size_t)(kt * 576 + lane) * 8;
#pragma unroll
        for (int nt = 0; nt < 9; nt++) {
            short8 b_hi = *(const short8*)(bh + nt * 512);
            short8 b_lo = *(const short8*)(bl + nt * 512);
            acc[nt] = __builtin_amdgcn_mfma_f32_16x16x32_bf16(a_hi, b_hi, acc[nt], 0, 0, 0);
            acc[nt] = __builtin_amdgcn_mfma_f32_16x16x32_bf16(a_lo, b_hi, acc[nt], 0, 0, 0);
            acc[nt] = __builtin_amdgcn_mfma_f32_16x16x32_bf16(a_hi, b_lo, acc[nt], 0, 0, 0);
        }
    }

    // C/D layout: col = lane&15, row = (lane>>4)*4 + reg (m89-verified)
    int q = lane >> 4, ncol = lane & 15;
    int rbase = wt * 16 + q * 4;
#pragma unroll
    for (int nt = 0; nt < 8; nt++) {
#pragma unroll
        for (int reg = 0; reg < 4; reg++) {
            int r = rbase + reg;
            if (r < n) hout[(size_t)r * D + nt * 16 + ncol] = f2bf(acc[nt][reg]);
        }
    }
#pragma unroll
    for (int reg = 0; reg < 4; reg++) {
        int r = rbase + reg;
        if (r < n) {
            float v = acc[8][reg];
            if (ncol < 8) as_[r * H + ncol] = v;
            else          ad_[r * H + (ncol - 8)] = v;
        }
    }
}

// ---------------- fused: CSR refine (LDS cursors) | layer-1 gemm ----------------
// Refine block rb: seed LDS cursors with poffs[bucket range], then per edge
// LDS returning atomicAdd -> unique global slot -> csrsrc store. No global
// returning atomics anywhere.

__global__ __launch_bounds__(256) void k_fillgemm(
    const int* __restrict__ poffs, const int* __restrict__ bkt,
    const int* __restrict__ bcur, int* __restrict__ csrsrc,
    ushortT* __restrict__ hbuf_s, float* __restrict__ asrc_s,
    const ushortT* __restrict__ xh, const ushortT* __restrict__ xl,
    const ushortT* __restrict__ wf_hi, const ushortT* __restrict__ wf_lo,
    ushortT* __restrict__ hout, float* __restrict__ as_,
    float* __restrict__ ad_, int n, int gb, int nbkt) {
    int b = blockIdx.x;
    int t = threadIdx.x;
    if (b < gb) {
        int wt = b * 4 + (t >> 6);
        if (wt * 16 < n)
            gemm_wave(wt, t & 63, xh, xl, wf_hi, wf_lo, hout, as_, ad_, n);
        return;
    }
    int rb = b - gb;
    if (rb < nbkt) {
        __shared__ int cur[BRANGE];
        int nb = rb * BRANGE;
        for (int i = t; i < BRANGE; i += 256) {
            int node = nb + i;
            cur[i] = (node < n) ? poffs[node] : 0;
        }
        __syncthreads();
        int tot = bcur[rb * 16];
        if (tot > CAP) tot = CAP;
        const int* bp = bkt + (size_t)rb * CAP;
        for (int i = t * 4; i < tot; i += 1024) {
            if (i + 3 < tot) {
                int4 v = *(const int4*)(bp + i);
                int s0 = atomicAdd(&cur[v.x >> 17], 1);
                int s1 = atomicAdd(&cur[v.y >> 17], 1);
                int s2 = atomicAdd(&cur[v.z >> 17], 1);
                int s3 = atomicAdd(&cur[v.w >> 17], 1);
                csrsrc[s0] = v.x & 0x1FFFF;
                csrsrc[s1] = v.y & 0x1FFFF;
                csrsrc[s2] = v.z & 0x1FFFF;
                csrsrc[s3] = v.w & 0x1FFFF;
            } else {
                for (int k = i; k < tot; k++) {
                    int v = bp[k];
                    int s = atomicAdd(&cur[v >> 17], 1);
                    csrsrc[s] = v & 0x1FFFF;
                }
            }
        }
        return;
    }
    if (rb == nbkt && t == 0) {
        int total = poffs[n];
        for (int k = 0; k < 8; k++) csrsrc[total + k] = n;        // slack
        for (int k = 0; k < D; k++) hbuf_s[(size_t)n * D + k] = 0; // sentinel row
        for (int h = 0; h < H; h++) asrc_s[n * H + h] = -1e30f;    // weight -> 0
    }
}

// ---------------- standalone gemm (layer 2) ----------------

__global__ __launch_bounds__(256) void k_gemm_att(
    const ushortT* __restrict__ xh, const ushortT* __restrict__ xl,
    const ushortT* __restrict__ wf_hi, const ushortT* __restrict__ wf_lo,
    ushortT* __restrict__ hout, float* __restrict__ as_,
    float* __restrict__ ad_, int n) {
    int t = threadIdx.x;
    int wt = blockIdx.x * 4 + (t >> 6);
    if (wt * 16 >= n) return;
    gemm_wave(wt, t & 63, xh, xl, wf_hi, wf_lo, hout, as_, ad_, n);
}

// ---------------- aggregate: 2 nodes/wave, stride-1, unroll x4, no guards -------
// Lanes 0-31 = node A, 32-63 = node B; lane ll owns channels ll*4..+3.
// out_mode 0: f32 final output. out_mode 1: relu, then bf16 hi/lo split
// written in A-frag order (feeds the next LDS-free gemm directly).

__global__ __launch_bounds__(256) void k_aggregate(
    const ushortT* __restrict__ hbuf, const float* __restrict__ asrc,
    const float* __restrict__ adst, const int* __restrict__ csr,
    const int* __restrict__ poffs, const float* __restrict__ bias,
    float* __restrict__ out, ushortT* __restrict__ oh, ushortT* __restrict__ ol,
    int out_mode, int n) {
    int t = threadIdx.x;
    int d = blockIdx.x * 8 + (t >> 5);
    if (d >= n) return;
    int ll = t & 31;
    int h = ll >> 2;

    int off = poffs[d];
    int degp = poffs[d + 1] - off;   // multiple of 4, >= 4
    float adh = adst[d * H + h];

    float4 acc0 = make_float4(0.f, 0.f, 0.f, 0.f);
    float4 acc1 = make_float4(0.f, 0.f, 0.f, 0.f);
    float ssum = 0.f;

    int s0 = csr[off + 0], s1 = csr[off + 1], s2 = csr[off + 2], s3 = csr[off + 3];
    for (int j = 0; j < degp; j += 4) {
        int p0 = csr[off + j + 4], p1 = csr[off + j + 5];
        int p2 = csr[off + j + 6], p3 = csr[off + j + 7];
        float e0 = asrc[s0 * H + h] + adh;
        float e1 = asrc[s1 * H + h] + adh;
        float e2 = asrc[s2 * H + h] + adh;
        float e3 = asrc[s3 * H + h] + adh;
        ushort4 u0 = *(const ushort4*)(hbuf + (size_t)s0 * D + ll * 4);
        ushort4 u1 = *(const ushort4*)(hbuf + (size_t)s1 * D + ll * 4);
        ushort4 u2 = *(const ushort4*)(hbuf + (size_t)s2 * D + ll * 4);
        ushort4 u3 = *(const ushort4*)(hbuf + (size_t)s3 * D + ll * 4);
        float w0 = __expf(e0 > 0.f ? e0 : NEG_SLOPE * e0);
        float w1 = __expf(e1 > 0.f ? e1 : NEG_SLOPE * e1);
        float w2 = __expf(e2 > 0.f ? e2 : NEG_SLOPE * e2);
        float w3 = __expf(e3 > 0.f ? e3 : NEG_SLOPE * e3);
        ssum += (w0 + w1) + (w2 + w3);
        acc0.x += w0 * bf2f(u0.x); acc0.y += w0 * bf2f(u0.y);
        acc0.z += w0 * bf2f(u0.z); acc0.w += w0 * bf2f(u0.w);
        acc1.x += w1 * bf2f(u1.x); acc1.y += w1 * bf2f(u1.y);
        acc1.z += w1 * bf2f(u1.z); acc1.w += w1 * bf2f(u1.w);
        acc0.x += w2 * bf2f(u2.x); acc0.y += w2 * bf2f(u2.y);
        acc0.z += w2 * bf2f(u2.z); acc0.w += w2 * bf2f(u2.w);
        acc1.x += w3 * bf2f(u3.x); acc1.y += w3 * bf2f(u3.y);
        acc1.z += w3 * bf2f(u3.z); acc1.w += w3 * bf2f(u3.w);
        s0 = p0; s1 = p1; s2 = p2; s3 = p3;
    }

    float inv = 1.f / ssum;
    float4 b = ((const float4*)bias)[ll];
    float4 r;
    r.x = (acc0.x + acc1.x) * inv + b.x;
    r.y = (acc0.y + acc1.y) * inv + b.y;
    r.z = (acc0.z + acc1.z) * inv + b.z;
    r.w = (acc0.w + acc1.w) * inv + b.w;

    if (out_mode == 0) {
        ((float4*)(out + (size_t)d * D))[ll] = r;
    } else {
        r.x = fmaxf(r.x, 0.f);
        r.y = fmaxf(r.y, 0.f);
        r.z = fmaxf(r.z, 0.f);
        r.w = fmaxf(r.w, 0.f);
        // A-frag address for (row d, cols ll*4..+3)
        int wt = d >> 4, m = d & 15;
        int kt = ll >> 3, quad = (ll >> 1) & 3, j0 = (ll & 1) * 4;
        int base = ((wt * 4 + kt) * 64 + (m + 16 * quad)) * 8 + j0;
        ushort4 hv, lv;
        hv.x = f2bf(r.x); lv.x = f2bf(r.x - bf2f(hv.x));
        hv.y = f2bf(r.y); lv.y = f2bf(r.y - bf2f(hv.y));
        hv.z = f2bf(r.z); lv.z = f2bf(r.z - bf2f(hv.z));
        hv.w = f2bf(r.w); lv.w = f2bf(r.w - bf2f(hv.w));
        *(ushort4*)(oh + base) = hv;
        *(ushort4*)(ol + base) = lv;
    }
}

// ---------------- launch ----------------

extern "C" void kernel_launch(void* const* d_in, const int* in_sizes, int n_in,
                              void* d_out, int out_size, void* d_ws, size_t ws_size,
                              hipStream_t stream) {
    const float* x   = (const float*)d_in[0];
    const int*   ei  = (const int*)d_in[1];
    const float* W1  = (const float*)d_in[2];
    const float* as1 = (const float*)d_in[3];
    const float* ad1 = (const float*)d_in[4];
    const float* b1  = (const float*)d_in[5];
    const float* W2  = (const float*)d_in[6];
    const float* as2 = (const float*)d_in[7];
    const float* ad2 = (const float*)d_in[8];
    const float* b2  = (const float*)d_in[9];
    float* out = (float*)d_out;

    int N = in_sizes[0] / D;
    int E = in_sizes[1] / 2;
    int NT16 = (N + 15) / 16;
    int nb_scan = (N + SCAN_TILE - 1) / SCAN_TILE;   // <= 64 assumed (N <= 64K)
    int nbkt = (N + BRANGE - 1) >> BSHIFT;           // <= 16 assumed
    const int WFN = 4 * 9 * 64 * 8;  // 18432 ushorts per wf buffer
    size_t XS = (size_t)NT16 * 2048; // ushorts per split buffer

    // workspace layout; sentinel row n in hbuf/asrc
    ushortT* hbuf = (ushortT*)d_ws;                        // (N+1)*D bf16
    ushortT* xsh  = hbuf + (size_t)(N + 1) * D;            // split hi (frag order)
    ushortT* xsl  = xsh + XS;                              // split lo
    float* asrc = (float*)(xsl + XS);                      // (N+1)*H
    float* adst = asrc + (size_t)(N + 1) * H;              // N*H
    int*   poffs  = (int*)(adst + (size_t)N * H);          // N+1
    int*   cursor = poffs + ((N + 1 + 3) & ~3);            // N (node counts)
    int*   sstate = cursor + ((N + 3) & ~3);               // 64 (lookback state)
    int*   bcur   = sstate + 64;                           // 16*16 bucket cursors
    int*   csrsrc = bcur + 256;                            // E + 4N + 8
    int*   bkt    = csrsrc + ((E + 4 * N + 8 + 3) & ~3);   // nbkt*CAP packed edges
    ushortT* wf1_hi = (ushortT*)(bkt + (size_t)nbkt * CAP);
    ushortT* wf1_lo = wf1_hi + WFN;
    ushortT* wf2_hi = wf1_lo + WFN;
    ushortT* wf2_lo = wf2_hi + WFN;

    // zero cursor + lookback state + bucket cursors in one memset
    hipMemsetAsync(cursor, 0, (size_t)(((N + 3) & ~3) + 64 + 256) * sizeof(int),
                   stream);

    int nbb = (E + BEDGES - 1) / BEDGES;
    int nbx = (NT16 * 16 * 16 + 255) / 256;  // xsplit: 16 threads/row
    k_prep<<<nbb + 18 + nbx, 256, 0, stream>>>(
        ei, bkt, bcur, E, x, xsh, xsl, N, NT16,
        W1, as1, ad1, W2, as2, ad2, wf1_hi, wf1_lo, wf2_hi, wf2_lo, nbb);

    k_count<<<nbkt * CSPLIT, 256, 0, stream>>>(bkt, bcur, cursor, N);

    k_scan_lb<<<nb_scan, 256, 0, stream>>>(cursor, poffs, sstate, csrsrc, N);

    int gb = (NT16 + 3) / 4;
    int ab = (N + 7) / 8;
    // layer 1: CSR refine | gemm fused
    k_fillgemm<<<gb + nbkt + 1, 256, 0, stream>>>(
        poffs, bkt, bcur, csrsrc, hbuf, asrc,
        xsh, xsl, wf1_hi, wf1_lo, hbuf, asrc, adst, N, gb, nbkt);
    k_aggregate<<<ab, 256, 0, stream>>>(hbuf, asrc, adst, csrsrc, poffs, b1,
                                        out, xsh, xsl, 1, N);
    // layer 2 (reads split frags produced by aggregate 1)
    k_gemm_att<<<gb, 256, 0, stream>>>(xsh, xsl, wf2_hi, wf2_lo, hbuf, asrc, adst, N);
    k_aggregate<<<ab, 256, 0, stream>>>(hbuf, asrc, adst, csrsrc, poffs, b2,
                                        out, xsh, xsl, 0, N);
}

// Round 3
// 240.897 us; speedup vs baseline: 1.2425x; 1.2425x over previous
//
#include <hip/hip_runtime.h>
#include <math.h>

#define D 128
#define H 8
#define C 16
#define NEG_SLOPE 0.2f
#define SCAN_TILE 1024  // elements per scan block (256 thr x 4)

// ---- bucket partition params (CSR build without global returning atomics) ----
#define BSHIFT 12
#define BRANGE 4096            // nodes per bucket (LDS counters = 16KB)
#define NBMAX 16               // compile-time max buckets (N <= 64K)
#define EPT 32                 // edges per thread in bucket pass
#define BEDGES (256 * EPT)     // 8192 edges per bucket block
#define CAP 98304              // per-bucket capacity (mean ~65.5K, ~130 sigma margin)
#define NSEG 16                // segments per bucket (refine/count parallelism)

typedef unsigned short ushortT;
typedef __attribute__((ext_vector_type(8))) short short8;
typedef __attribute__((ext_vector_type(4))) float f32x4;

// bf16 <-> f32 helpers (RNE pack; no NaN inputs here)
__device__ __forceinline__ float bf2f(unsigned short v) {
    union { unsigned int i; float f; } c;
    c.i = ((unsigned int)v) << 16;
    return c.f;
}
__device__ __forceinline__ unsigned short f2bf(float f) {
    union { float f; unsigned int i; } c;
    c.f = f;
    unsigned int lsb = (c.i >> 16) & 1u;
    c.i += 0x7fffu + lsb;
    return (unsigned short)(c.i >> 16);
}

// padded count per node = (cnt + 1 self-loop + 3) & ~3  (>= 4, multiple of 4)
__device__ __forceinline__ int padc(int c) { return (c + 4) & ~3; }

// A-frag address for element (row r, col k):
// wt=r>>4, m=r&15, kt=k>>5, quad=(k>>3)&3, j=k&7, lane=m+16*quad
// addr = ((wt*4+kt)*64 + lane)*8 + j     (2048 ushorts per 16x128 tile)

// ---------------- fused prep: bucket | wprep | xsplit (independent) --------------
// bucket: 2-pass register-counter partition by dst>>12. Ranks via wave shfl
// prefix + 16 returning atomics PER BLOCK (total ~1.6K, vs 800K per-edge).
// Edge packed as (local_dst<<17)|src in one int (local_dst<4096, src<131072).

__device__ __forceinline__ void bucket_part(
    int b, int t, const int* __restrict__ ei, int* __restrict__ bkt,
    int* __restrict__ bcur, int E) {
    __shared__ int wtot[4][NBMAX];
    __shared__ int wbase[4][NBMAX];
    int w = t >> 6, lane = t & 63;
    int base = b * BEDGES;

    int cnt[NBMAX];
#pragma unroll
    for (int q = 0; q < NBMAX; q++) cnt[q] = 0;

    // pass 1: count per bucket (compile-time-indexed register counters)
#pragma unroll
    for (int it = 0; it < EPT / 4; it++) {
        int idx = base + it * 1024 + t * 4;
        if (idx + 3 < E) {
            int4 dv = *(const int4*)(ei + (size_t)E + idx);
            int b0 = dv.x >> BSHIFT, b1 = dv.y >> BSHIFT;
            int b2 = dv.z >> BSHIFT, b3 = dv.w >> BSHIFT;
#pragma unroll
            for (int q = 0; q < NBMAX; q++)
                cnt[q] += (b0 == q) + (b1 == q) + (b2 == q) + (b3 == q);
        } else {
            for (int k = idx; k < E && k < idx + 4; k++) {
                int bq = ei[(size_t)E + k] >> BSHIFT;
#pragma unroll
                for (int q = 0; q < NBMAX; q++) cnt[q] += (bq == q);
            }
        }
    }

    // wave-level exclusive prefix per bucket
    int pre[NBMAX];
#pragma unroll
    for (int q = 0; q < NBMAX; q++) {
        int p = cnt[q];
#pragma unroll
        for (int o = 1; o < 64; o <<= 1) {
            int v = __shfl_up(p, o);
            if (lane >= o) p += v;
        }
        pre[q] = p - cnt[q];
        if (lane == 63) wtot[w][q] = p;
    }
    __syncthreads();
    if (t < NBMAX) {
        int q = t;
        int s0 = wtot[0][q], s1 = wtot[1][q], s2 = wtot[2][q], s3 = wtot[3][q];
        int tot = s0 + s1 + s2 + s3;
        int gb = (tot > 0) ? atomicAdd(bcur + q * 16, tot) : 0;
        wbase[0][q] = gb;
        wbase[1][q] = gb + s0;
        wbase[2][q] = gb + s0 + s1;
        wbase[3][q] = gb + s0 + s1 + s2;
    }
    __syncthreads();
    int cur[NBMAX];
#pragma unroll
    for (int q = 0; q < NBMAX; q++) cur[q] = wbase[w][q] + pre[q];

    // pass 2: place (one store per edge; cndmask select chain for the cursor)
#pragma unroll
    for (int it = 0; it < EPT / 4; it++) {
        int idx = base + it * 1024 + t * 4;
        if (idx + 3 < E) {
            int4 sv = *(const int4*)(ei + idx);
            int4 dv = *(const int4*)(ei + (size_t)E + idx);
            int dd[4] = {dv.x, dv.y, dv.z, dv.w};
            int ss[4] = {sv.x, sv.y, sv.z, sv.w};
#pragma unroll
            for (int e = 0; e < 4; e++) {
                int bq = dd[e] >> BSHIFT;
                int pk = ((dd[e] & (BRANGE - 1)) << 17) | ss[e];
                int off = cur[0];
#pragma unroll
                for (int q = 1; q < NBMAX; q++) off = (bq == q) ? cur[q] : off;
                if (off < CAP) bkt[(size_t)bq * CAP + off] = pk;
#pragma unroll
                for (int q = 0; q < NBMAX; q++) cur[q] += (bq == q);
            }
        } else {
            for (int k = idx; k < E && k < idx + 4; k++) {
                int d = ei[(size_t)E + k], s = ei[k];
                int bq = d >> BSHIFT;
                int pk = ((d & (BRANGE - 1)) << 17) | s;
                int off = cur[0];
#pragma unroll
                for (int q = 1; q < NBMAX; q++) off = (bq == q) ? cur[q] : off;
                if (off < CAP) bkt[(size_t)bq * CAP + off] = pk;
#pragma unroll
                for (int q = 0; q < NBMAX; q++) cur[q] += (bq == q);
            }
        }
    }
}

__device__ __forceinline__ void wprep_part(
    int b2, int t, const float* __restrict__ W1, const float* __restrict__ as1,
    const float* __restrict__ ad1, const float* __restrict__ W2,
    const float* __restrict__ as2, const float* __restrict__ ad2,
    ushortT* __restrict__ wf1_hi, ushortT* __restrict__ wf1_lo,
    ushortT* __restrict__ wf2_hi, ushortT* __restrict__ wf2_lo) {
    const float *W, *att_s, *att_d;
    ushortT *whi, *wlo;
    int idx;
    if (b2 < 9) {
        W = W1; att_s = as1; att_d = ad1; whi = wf1_hi; wlo = wf1_lo;
        idx = b2 * 256 + t;
    } else {
        W = W2; att_s = as2; att_d = ad2; whi = wf2_hi; wlo = wf2_lo;
        idx = (b2 - 9) * 256 + t;
    }
    if (idx >= 4 * 9 * 64) return;
    int lane = idx & 63;
    int nt = (idx >> 6) % 9;
    int kt = idx / (9 * 64);
    int quad = lane >> 4, ncol = lane & 15;
#pragma unroll
    for (int j = 0; j < 8; j++) {
        int k = kt * 32 + quad * 8 + j;
        float v;
        if (nt < 8) {
            v = W[k * D + nt * 16 + ncol];
        } else {
            const float* att = (ncol < 8) ? att_s : att_d;
            int hd = ncol & 7;
            float s = 0.f;
            for (int c = 0; c < 16; c++)
                s += W[k * D + hd * 16 + c] * att[hd * 16 + c];
            v = s;
        }
        unsigned short hi = f2bf(v);
        unsigned short lo = f2bf(v - bf2f(hi));
        whi[idx * 8 + j] = hi;
        wlo[idx * 8 + j] = lo;
    }
}

__device__ __forceinline__ void xsplit_part(
    int idx, const float* __restrict__ x, ushortT* __restrict__ xh,
    ushortT* __restrict__ xl, int n, int nt16) {
    int r = idx >> 4;
    if (r >= nt16 * 16) return;
    int kb = idx & 15;
    float4 v0 = make_float4(0.f, 0.f, 0.f, 0.f), v1 = v0;
    if (r < n) {
        v0 = ((const float4*)(x + (size_t)r * D + kb * 8))[0];
        v1 = ((const float4*)(x + (size_t)r * D + kb * 8))[1];
    }
    int wt = r >> 4, m = r & 15, kt = kb >> 2, quad = kb & 3;
    int base = ((wt * 4 + kt) * 64 + (m + 16 * quad)) * 8;
    ushort4 h0, l0, h1, l1;
    h0.x = f2bf(v0.x); l0.x = f2bf(v0.x - bf2f(h0.x));
    h0.y = f2bf(v0.y); l0.y = f2bf(v0.y - bf2f(h0.y));
    h0.z = f2bf(v0.z); l0.z = f2bf(v0.z - bf2f(h0.z));
    h0.w = f2bf(v0.w); l0.w = f2bf(v0.w - bf2f(h0.w));
    h1.x = f2bf(v1.x); l1.x = f2bf(v1.x - bf2f(h1.x));
    h1.y = f2bf(v1.y); l1.y = f2bf(v1.y - bf2f(h1.y));
    h1.z = f2bf(v1.z); l1.z = f2bf(v1.z - bf2f(h1.z));
    h1.w = f2bf(v1.w); l1.w = f2bf(v1.w - bf2f(h1.w));
    *(ushort4*)(xh + base) = h0;
    *(ushort4*)(xh + base + 4) = h1;
    *(ushort4*)(xl + base) = l0;
    *(ushort4*)(xl + base + 4) = l1;
}

__global__ __launch_bounds__(256) void k_prep(
    const int* __restrict__ ei, int* __restrict__ bkt, int* __restrict__ bcur,
    int E, const float* __restrict__ x, ushortT* __restrict__ xh,
    ushortT* __restrict__ xl, int n, int nt16,
    const float* __restrict__ W1, const float* __restrict__ as1,
    const float* __restrict__ ad1, const float* __restrict__ W2,
    const float* __restrict__ as2, const float* __restrict__ ad2,
    ushortT* __restrict__ wf1_hi, ushortT* __restrict__ wf1_lo,
    ushortT* __restrict__ wf2_hi, ushortT* __restrict__ wf2_lo, int nbb) {
    int b = blockIdx.x;
    int t = threadIdx.x;
    if (b < nbb) {
        bucket_part(b, t, ei, bkt, bcur, E);
    } else if (b < nbb + 18) {
        wprep_part(b - nbb, t, W1, as1, ad1, W2, as2, ad2,
                   wf1_hi, wf1_lo, wf2_hi, wf2_lo);
    } else {
        xsplit_part((b - nbb - 18) * 256 + t, x, xh, xl, n, nt16);
    }
}

// ---------------- per-(bucket,segment) LDS histogram -> hseg (no atomics) -------

__global__ __launch_bounds__(256) void k_count(
    const int* __restrict__ bkt, const int* __restrict__ bcur,
    int* __restrict__ hseg, int n) {
    __shared__ int lcnt[BRANGE];
    int t = threadIdx.x;
    int q = blockIdx.x >> 4, s = blockIdx.x & (NSEG - 1);
    for (int i = t; i < BRANGE; i += 256) lcnt[i] = 0;
    __syncthreads();
    int tot = bcur[q * 16];
    if (tot > CAP) tot = CAP;
    int per = ((tot + NSEG - 1) / NSEG + 3) & ~3;   // 4-aligned split
    int lo = s * per;
    int hi = lo + per; if (hi > tot) hi = tot;
    const int* bp = bkt + (size_t)q * CAP;
    for (int i = lo + t * 4; i < hi; i += 1024) {
        if (i + 3 < hi) {
            int4 v = *(const int4*)(bp + i);
            atomicAdd(&lcnt[v.x >> 17], 1);
            atomicAdd(&lcnt[v.y >> 17], 1);
            atomicAdd(&lcnt[v.z >> 17], 1);
            atomicAdd(&lcnt[v.w >> 17], 1);
        } else {
            for (int k = i; k < hi; k++) atomicAdd(&lcnt[bp[k] >> 17], 1);
        }
    }
    __syncthreads();
    int* hp = hseg + ((size_t)(q * NSEG + s) << BSHIFT);
    for (int i = t; i < BRANGE; i += 256) hp[i] = lcnt[i];
}

// ---------------- single-pass decoupled-lookback scan + self-loop/pads ----------
// <=64 blocks, all co-resident on 256 CUs -> spin-free-deadlock guaranteed.
// Node counts = sum of the NSEG segment histograms (registers). After poffs is
// known, hseg is overwritten IN PLACE with per-segment exclusive bases:
// sbase[q][s][node] = poffs[node] + sum_{s'<s} hseg[q][s'][node]. Refine blocks
// then own disjoint slot ranges with zero cross-block coordination.

__global__ __launch_bounds__(256) void k_scan_lb(
    int* __restrict__ hseg, int* __restrict__ poffs,
    int* __restrict__ sstate, int* __restrict__ csrsrc, int n) {
    __shared__ int lds[256];
    __shared__ int bprefix;
    int t = threadIdx.x;
    int b = blockIdx.x;
    int base = b * SCAN_TILE + t * 4;      // SCAN_TILE divides BRANGE ->
    int q = base >> BSHIFT;                // all 4 nodes in one bucket
    int li = base & (BRANGE - 1);
    int4 hv[NSEG];
    int c[4] = {0, 0, 0, 0};
    bool any = (base < n);
    if (any) {
#pragma unroll
        for (int s = 0; s < NSEG; s++) {
            hv[s] = *(const int4*)(hseg + ((size_t)(q * NSEG + s) << BSHIFT) + li);
            c[0] += hv[s].x; c[1] += hv[s].y; c[2] += hv[s].z; c[3] += hv[s].w;
        }
    }
    int ssum = padc(c[0]) + padc(c[1]) + padc(c[2]) + padc(c[3]);
    lds[t] = ssum;
    __syncthreads();
    for (int st = 1; st < 256; st <<= 1) {
        int add = (t >= st) ? lds[t - st] : 0;
        __syncthreads();
        lds[t] += add;
        __syncthreads();
    }
    if (t == 0)
        __hip_atomic_store(&sstate[b], lds[255] | (1 << 30),
                           __ATOMIC_RELEASE, __HIP_MEMORY_SCOPE_AGENT);
    if (t < 64) {
        int v = 0;
        if (t < b) {
            int x;
            do {
                x = __hip_atomic_load(&sstate[t], __ATOMIC_RELAXED,
                                      __HIP_MEMORY_SCOPE_AGENT);
            } while (!(x & (1 << 30)));
            v = x & 0x3FFFFFFF;
        }
#pragma unroll
        for (int o = 32; o > 0; o >>= 1) v += __shfl_down(v, o);
        if (t == 0) bprefix = v;
    }
    __syncthreads();
    int run = bprefix + ((t == 0) ? 0 : lds[t - 1]);
    if (b == 0 && t == 0) poffs[0] = 0;
    int runk[4];
#pragma unroll
    for (int k = 0; k < 4; k++) {
        int i = base + k;
        runk[k] = run;
        if (i < n) {
            int pv = padc(c[k]);
            csrsrc[run + c[k]] = i;                        // self-loop last
            for (int k2 = c[k] + 1; k2 < pv; k2++)
                csrsrc[run + k2] = n;                      // sentinel pads
            run += pv;
            poffs[i + 1] = run;
        }
    }
    if (any) {
        int a0 = runk[0], a1 = runk[1], a2 = runk[2], a3 = runk[3];
#pragma unroll
        for (int s = 0; s < NSEG; s++) {
            int4 v = hv[s];
            int4 w; w.x = a0; w.y = a1; w.z = a2; w.w = a3;
            *(int4*)(hseg + ((size_t)(q * NSEG + s) << BSHIFT) + li) = w;
            a0 += v.x; a1 += v.y; a2 += v.z; a3 += v.w;
        }
    }
}

// ---------------- gemm wave body (split-bf16 MFMA, LDS-free) ----------------

__device__ __forceinline__ void gemm_wave(
    int wt, int lane, const ushortT* __restrict__ xh,
    const ushortT* __restrict__ xl, const ushortT* __restrict__ wf_hi,
    const ushortT* __restrict__ wf_lo, ushortT* __restrict__ hout,
    float* __restrict__ as_, float* __restrict__ ad_, int n) {
    f32x4 acc[9];
#pragma unroll
    for (int nt = 0; nt < 9; nt++) acc[nt] = (f32x4){0.f, 0.f, 0.f, 0.f};

#pragma unroll
    for (int kt = 0; kt < 4; kt++) {
        short8 a_hi = *(const short8*)(xh + (size_t)((wt * 4 + kt) * 64 + lane) * 8);
        short8 a_lo = *(const short8*)(xl + (size_t)((wt * 4 + kt) * 64 + lane) * 8);
        const ushortT* bh = wf_hi + (size_t)(kt * 576 + lane) * 8;
        const ushortT* bl = wf_lo + (size_t)(kt * 576 + lane) * 8;
#pragma unroll
        for (int nt = 0; nt < 9; nt++) {
            short8 b_hi = *(const short8*)(bh + nt * 512);
            short8 b_lo = *(const short8*)(bl + nt * 512);
            acc[nt] = __builtin_amdgcn_mfma_f32_16x16x32_bf16(a_hi, b_hi, acc[nt], 0, 0, 0);
            acc[nt] = __builtin_amdgcn_mfma_f32_16x16x32_bf16(a_lo, b_hi, acc[nt], 0, 0, 0);
            acc[nt] = __builtin_amdgcn_mfma_f32_16x16x32_bf16(a_hi, b_lo, acc[nt], 0, 0, 0);
        }
    }

    // C/D layout: col = lane&15, row = (lane>>4)*4 + reg (m89-verified)
    int q = lane >> 4, ncol = lane & 15;
    int rbase = wt * 16 + q * 4;
#pragma unroll
    for (int nt = 0; nt < 8; nt++) {
#pragma unroll
        for (int reg = 0; reg < 4; reg++) {
            int r = rbase + reg;
            if (r < n) hout[(size_t)r * D + nt * 16 + ncol] = f2bf(acc[nt][reg]);
        }
    }
#pragma unroll
    for (int reg = 0; reg < 4; reg++) {
        int r = rbase + reg;
        if (r < n) {
            float v = acc[8][reg];
            if (ncol < 8) as_[r * H + ncol] = v;
            else          ad_[r * H + (ncol - 8)] = v;
        }
    }
}

// ---------------- fused: CSR refine (segment-parallel) | layer-1 gemm -----------
// Refine block (q,s): seed LDS cursors from the in-place sbase slice of hseg,
// then per edge LDS returning atomicAdd -> unique global slot -> csrsrc store.
// nbkt*NSEG refine blocks overlap the gemm blocks; no global returning atomics.

__global__ __launch_bounds__(256) void k_fillgemm(
    const int* __restrict__ poffs, const int* __restrict__ bkt,
    const int* __restrict__ bcur, const int* __restrict__ hseg,
    int* __restrict__ csrsrc,
    ushortT* __restrict__ hbuf_s, float* __restrict__ asrc_s,
    const ushortT* __restrict__ xh, const ushortT* __restrict__ xl,
    const ushortT* __restrict__ wf_hi, const ushortT* __restrict__ wf_lo,
    ushortT* __restrict__ hout, float* __restrict__ as_,
    float* __restrict__ ad_, int n, int gb, int nrb) {
    int b = blockIdx.x;
    int t = threadIdx.x;
    if (b < gb) {
        int wt = b * 4 + (t >> 6);
        if (wt * 16 < n)
            gemm_wave(wt, t & 63, xh, xl, wf_hi, wf_lo, hout, as_, ad_, n);
        return;
    }
    int rb = b - gb;
    if (rb < nrb) {
        __shared__ int cur[BRANGE];
        int q = rb >> 4, s = rb & (NSEG - 1);
        const int* sp = hseg + ((size_t)(q * NSEG + s) << BSHIFT);
        for (int i = t; i < BRANGE; i += 256) cur[i] = sp[i];
        __syncthreads();
        int tot = bcur[q * 16];
        if (tot > CAP) tot = CAP;
        int per = ((tot + NSEG - 1) / NSEG + 3) & ~3;
        int lo = s * per;
        int hi = lo + per; if (hi > tot) hi = tot;
        const int* bp = bkt + (size_t)q * CAP;
        for (int i = lo + t * 4; i < hi; i += 1024) {
            if (i + 3 < hi) {
                int4 v = *(const int4*)(bp + i);
                int s0 = atomicAdd(&cur[v.x >> 17], 1);
                int s1 = atomicAdd(&cur[v.y >> 17], 1);
                int s2 = atomicAdd(&cur[v.z >> 17], 1);
                int s3 = atomicAdd(&cur[v.w >> 17], 1);
                csrsrc[s0] = v.x & 0x1FFFF;
                csrsrc[s1] = v.y & 0x1FFFF;
                csrsrc[s2] = v.z & 0x1FFFF;
                csrsrc[s3] = v.w & 0x1FFFF;
            } else {
                for (int k = i; k < hi; k++) {
                    int v = bp[k];
                    int sl = atomicAdd(&cur[v >> 17], 1);
                    csrsrc[sl] = v & 0x1FFFF;
                }
            }
        }
        return;
    }
    if (rb == nrb && t == 0) {
        int total = poffs[n];
        for (int k = 0; k < 8; k++) csrsrc[total + k] = n;        // slack
        for (int k = 0; k < D; k++) hbuf_s[(size_t)n * D + k] = 0; // sentinel row
        for (int h = 0; h < H; h++) asrc_s[n * H + h] = -1e30f;    // weight -> 0
    }
}

// ---------------- standalone gemm (layer 2) ----------------

__global__ __launch_bounds__(256) void k_gemm_att(
    const ushortT* __restrict__ xh, const ushortT* __restrict__ xl,
    const ushortT* __restrict__ wf_hi, const ushortT* __restrict__ wf_lo,
    ushortT* __restrict__ hout, float* __restrict__ as_,
    float* __restrict__ ad_, int n) {
    int t = threadIdx.x;
    int wt = blockIdx.x * 4 + (t >> 6);
    if (wt * 16 >= n) return;
    gemm_wave(wt, t & 63, xh, xl, wf_hi, wf_lo, hout, as_, ad_, n);
}

// ---------------- aggregate: 2 nodes/wave, stride-1, unroll x4, no guards -------
// Lanes 0-31 = node A, 32-63 = node B; lane ll owns channels ll*4..+3.
// out_mode 0: f32 final output. out_mode 1: relu, then bf16 hi/lo split
// written in A-frag order (feeds the next LDS-free gemm directly).

__global__ __launch_bounds__(256) void k_aggregate(
    const ushortT* __restrict__ hbuf, const float* __restrict__ asrc,
    const float* __restrict__ adst, const int* __restrict__ csr,
    const int* __restrict__ poffs, const float* __restrict__ bias,
    float* __restrict__ out, ushortT* __restrict__ oh, ushortT* __restrict__ ol,
    int out_mode, int n) {
    int t = threadIdx.x;
    int d = blockIdx.x * 8 + (t >> 5);
    if (d >= n) return;
    int ll = t & 31;
    int h = ll >> 2;

    int off = poffs[d];
    int degp = poffs[d + 1] - off;   // multiple of 4, >= 4
    float adh = adst[d * H + h];

    float4 acc0 = make_float4(0.f, 0.f, 0.f, 0.f);
    float4 acc1 = make_float4(0.f, 0.f, 0.f, 0.f);
    float ssum = 0.f;

    int s0 = csr[off + 0], s1 = csr[off + 1], s2 = csr[off + 2], s3 = csr[off + 3];
    for (int j = 0; j < degp; j += 4) {
        int p0 = csr[off + j + 4], p1 = csr[off + j + 5];
        int p2 = csr[off + j + 6], p3 = csr[off + j + 7];
        float e0 = asrc[s0 * H + h] + adh;
        float e1 = asrc[s1 * H + h] + adh;
        float e2 = asrc[s2 * H + h] + adh;
        float e3 = asrc[s3 * H + h] + adh;
        ushort4 u0 = *(const ushort4*)(hbuf + (size_t)s0 * D + ll * 4);
        ushort4 u1 = *(const ushort4*)(hbuf + (size_t)s1 * D + ll * 4);
        ushort4 u2 = *(const ushort4*)(hbuf + (size_t)s2 * D + ll * 4);
        ushort4 u3 = *(const ushort4*)(hbuf + (size_t)s3 * D + ll * 4);
        float w0 = __expf(e0 > 0.f ? e0 : NEG_SLOPE * e0);
        float w1 = __expf(e1 > 0.f ? e1 : NEG_SLOPE * e1);
        float w2 = __expf(e2 > 0.f ? e2 : NEG_SLOPE * e2);
        float w3 = __expf(e3 > 0.f ? e3 : NEG_SLOPE * e3);
        ssum += (w0 + w1) + (w2 + w3);
        acc0.x += w0 * bf2f(u0.x); acc0.y += w0 * bf2f(u0.y);
        acc0.z += w0 * bf2f(u0.z); acc0.w += w0 * bf2f(u0.w);
        acc1.x += w1 * bf2f(u1.x); acc1.y += w1 * bf2f(u1.y);
        acc1.z += w1 * bf2f(u1.z); acc1.w += w1 * bf2f(u1.w);
        acc0.x += w2 * bf2f(u2.x); acc0.y += w2 * bf2f(u2.y);
        acc0.z += w2 * bf2f(u2.z); acc0.w += w2 * bf2f(u2.w);
        acc1.x += w3 * bf2f(u3.x); acc1.y += w3 * bf2f(u3.y);
        acc1.z += w3 * bf2f(u3.z); acc1.w += w3 * bf2f(u3.w);
        s0 = p0; s1 = p1; s2 = p2; s3 = p3;
    }

    float inv = 1.f / ssum;
    float4 b = ((const float4*)bias)[ll];
    float4 r;
    r.x = (acc0.x + acc1.x) * inv + b.x;
    r.y = (acc0.y + acc1.y) * inv + b.y;
    r.z = (acc0.z + acc1.z) * inv + b.z;
    r.w = (acc0.w + acc1.w) * inv + b.w;

    if (out_mode == 0) {
        ((float4*)(out + (size_t)d * D))[ll] = r;
    } else {
        r.x = fmaxf(r.x, 0.f);
        r.y = fmaxf(r.y, 0.f);
        r.z = fmaxf(r.z, 0.f);
        r.w = fmaxf(r.w, 0.f);
        // A-frag address for (row d, cols ll*4..+3)
        int wt = d >> 4, m = d & 15;
        int kt = ll >> 3, quad = (ll >> 1) & 3, j0 = (ll & 1) * 4;
        int base = ((wt * 4 + kt) * 64 + (m + 16 * quad)) * 8 + j0;
        ushort4 hv, lv;
        hv.x = f2bf(r.x); lv.x = f2bf(r.x - bf2f(hv.x));
        hv.y = f2bf(r.y); lv.y = f2bf(r.y - bf2f(hv.y));
        hv.z = f2bf(r.z); lv.z = f2bf(r.z - bf2f(hv.z));
        hv.w = f2bf(r.w); lv.w = f2bf(r.w - bf2f(hv.w));
        *(ushort4*)(oh + base) = hv;
        *(ushort4*)(ol + base) = lv;
    }
}

// ---------------- launch ----------------

extern "C" void kernel_launch(void* const* d_in, const int* in_sizes, int n_in,
                              void* d_out, int out_size, void* d_ws, size_t ws_size,
                              hipStream_t stream) {
    const float* x   = (const float*)d_in[0];
    const int*   ei  = (const int*)d_in[1];
    const float* W1  = (const float*)d_in[2];
    const float* as1 = (const float*)d_in[3];
    const float* ad1 = (const float*)d_in[4];
    const float* b1  = (const float*)d_in[5];
    const float* W2  = (const float*)d_in[6];
    const float* as2 = (const float*)d_in[7];
    const float* ad2 = (const float*)d_in[8];
    const float* b2  = (const float*)d_in[9];
    float* out = (float*)d_out;

    int N = in_sizes[0] / D;
    int E = in_sizes[1] / 2;
    int NT16 = (N + 15) / 16;
    int nb_scan = (N + SCAN_TILE - 1) / SCAN_TILE;   // <= 64 assumed (N <= 64K)
    int nbkt = (N + BRANGE - 1) >> BSHIFT;           // <= 16 assumed
    int nrb = nbkt * NSEG;                           // refine/count blocks
    const int WFN = 4 * 9 * 64 * 8;  // 18432 ushorts per wf buffer
    size_t XS = (size_t)NT16 * 2048; // ushorts per split buffer

    // workspace layout; sentinel row n in hbuf/asrc
    ushortT* hbuf = (ushortT*)d_ws;                        // (N+1)*D bf16
    ushortT* xsh  = hbuf + (size_t)(N + 1) * D;            // split hi (frag order)
    ushortT* xsl  = xsh + XS;                              // split lo
    float* asrc = (float*)(xsl + XS);                      // (N+1)*H
    float* adst = asrc + (size_t)(N + 1) * H;              // N*H
    int*   poffs  = (int*)(adst + (size_t)N * H);          // N+1
    int*   sstate = poffs + ((N + 1 + 3) & ~3);            // 64 (lookback state)
    int*   bcur   = sstate + 64;                           // 16*16 bucket cursors
    int*   csrsrc = bcur + 256;                            // E + 4N + 8
    int*   bkt    = csrsrc + ((E + 4 * N + 8 + 3) & ~3);   // nbkt*CAP packed edges
    int*   hseg   = bkt + (size_t)nbkt * CAP;              // nrb*BRANGE seg hists
    ushortT* wf1_hi = (ushortT*)(hseg + (size_t)nrb * BRANGE);
    ushortT* wf1_lo = wf1_hi + WFN;
    ushortT* wf2_hi = wf1_lo + WFN;
    ushortT* wf2_lo = wf2_hi + WFN;

    // zero lookback state + bucket cursors (hseg fully written by k_count)
    hipMemsetAsync(sstate, 0, 320 * sizeof(int), stream);

    int nbb = (E + BEDGES - 1) / BEDGES;
    int nbx = (NT16 * 16 * 16 + 255) / 256;  // xsplit: 16 threads/row
    k_prep<<<nbb + 18 + nbx, 256, 0, stream>>>(
        ei, bkt, bcur, E, x, xsh, xsl, N, NT16,
        W1, as1, ad1, W2, as2, ad2, wf1_hi, wf1_lo, wf2_hi, wf2_lo, nbb);

    k_count<<<nrb, 256, 0, stream>>>(bkt, bcur, hseg, N);

    k_scan_lb<<<nb_scan, 256, 0, stream>>>(hseg, poffs, sstate, csrsrc, N);

    int gb = (NT16 + 3) / 4;
    int ab = (N + 7) / 8;
    // layer 1: CSR refine | gemm fused
    k_fillgemm<<<gb + nrb + 1, 256, 0, stream>>>(
        poffs, bkt, bcur, hseg, csrsrc, hbuf, asrc,
        xsh, xsl, wf1_hi, wf1_lo, hbuf, asrc, adst, N, gb, nrb);
    k_aggregate<<<ab, 256, 0, stream>>>(hbuf, asrc, adst, csrsrc, poffs, b1,
                                        out, xsh, xsl, 1, N);
    // layer 2 (reads split frags produced by aggregate 1)
    k_gemm_att<<<gb, 256, 0, stream>>>(xsh, xsl, wf2_hi, wf2_lo, hbuf, asrc, adst, N);
    k_aggregate<<<ab, 256, 0, stream>>>(hbuf, asrc, adst, csrsrc, poffs, b2,
                                        out, xsh, xsl, 0, N);
}

// Round 4
// 239.254 us; speedup vs baseline: 1.2510x; 1.0069x over previous
//
#include <hip/hip_runtime.h>
#include <math.h>

#define D 128
#define H 8
#define C 16
#define NEG_SLOPE 0.2f
#define SCAN_TILE 1024  // elements per scan block (256 thr x 4)

// ---- bucket partition params (CSR build without global returning atomics) ----
#define BSHIFT 12
#define BRANGE 4096            // nodes per bucket (LDS counters = 16KB)
#define NBMAX 16               // compile-time max buckets (N <= 64K)
#define EPT 32                 // edges per thread in bucket pass
#define BEDGES (256 * EPT)     // 8192 edges per bucket block
#define CAP 98304              // per-bucket capacity (mean ~65.5K, ~130 sigma margin)
#define NSEG 16                // segments per bucket (refine/count parallelism)

typedef unsigned short ushortT;
typedef __attribute__((ext_vector_type(8))) short short8;
typedef __attribute__((ext_vector_type(4))) float f32x4;

// bf16 <-> f32 helpers (RNE pack; no NaN inputs here)
__device__ __forceinline__ float bf2f(unsigned short v) {
    union { unsigned int i; float f; } c;
    c.i = ((unsigned int)v) << 16;
    return c.f;
}
__device__ __forceinline__ unsigned short f2bf(float f) {
    union { float f; unsigned int i; } c;
    c.f = f;
    unsigned int lsb = (c.i >> 16) & 1u;
    c.i += 0x7fffu + lsb;
    return (unsigned short)(c.i >> 16);
}

// padded count per node = (cnt + 1 self-loop + 3) & ~3  (>= 4, multiple of 4)
__device__ __forceinline__ int padc(int c) { return (c + 4) & ~3; }

// A-frag address for element (row r, col k):
// wt=r>>4, m=r&15, kt=k>>5, quad=(k>>3)&3, j=k&7, lane=m+16*quad
// addr = ((wt*4+kt)*64 + lane)*8 + j     (2048 ushorts per 16x128 tile)

// ---------------- fused prep: bucket | wprep | xsplit (independent) --------------
// bucket: 2-pass register-counter partition by dst>>12. Ranks via wave shfl
// prefix + 16 returning atomics PER BLOCK (total ~1.6K, vs 800K per-edge).
// Edge packed as (local_dst<<17)|src in one int (local_dst<4096, src<131072).

__device__ __forceinline__ void bucket_part(
    int b, int t, const int* __restrict__ ei, int* __restrict__ bkt,
    int* __restrict__ bcur, int E) {
    __shared__ int wtot[4][NBMAX];
    __shared__ int wbase[4][NBMAX];
    int w = t >> 6, lane = t & 63;
    int base = b * BEDGES;

    int cnt[NBMAX];
#pragma unroll
    for (int q = 0; q < NBMAX; q++) cnt[q] = 0;

    // pass 1: count per bucket (compile-time-indexed register counters)
#pragma unroll
    for (int it = 0; it < EPT / 4; it++) {
        int idx = base + it * 1024 + t * 4;
        if (idx + 3 < E) {
            int4 dv = *(const int4*)(ei + (size_t)E + idx);
            int b0 = dv.x >> BSHIFT, b1 = dv.y >> BSHIFT;
            int b2 = dv.z >> BSHIFT, b3 = dv.w >> BSHIFT;
#pragma unroll
            for (int q = 0; q < NBMAX; q++)
                cnt[q] += (b0 == q) + (b1 == q) + (b2 == q) + (b3 == q);
        } else {
            for (int k = idx; k < E && k < idx + 4; k++) {
                int bq = ei[(size_t)E + k] >> BSHIFT;
#pragma unroll
                for (int q = 0; q < NBMAX; q++) cnt[q] += (bq == q);
            }
        }
    }

    // wave-level exclusive prefix per bucket
    int pre[NBMAX];
#pragma unroll
    for (int q = 0; q < NBMAX; q++) {
        int p = cnt[q];
#pragma unroll
        for (int o = 1; o < 64; o <<= 1) {
            int v = __shfl_up(p, o);
            if (lane >= o) p += v;
        }
        pre[q] = p - cnt[q];
        if (lane == 63) wtot[w][q] = p;
    }
    __syncthreads();
    if (t < NBMAX) {
        int q = t;
        int s0 = wtot[0][q], s1 = wtot[1][q], s2 = wtot[2][q], s3 = wtot[3][q];
        int tot = s0 + s1 + s2 + s3;
        int gb = (tot > 0) ? atomicAdd(bcur + q * 16, tot) : 0;
        wbase[0][q] = gb;
        wbase[1][q] = gb + s0;
        wbase[2][q] = gb + s0 + s1;
        wbase[3][q] = gb + s0 + s1 + s2;
    }
    __syncthreads();
    int cur[NBMAX];
#pragma unroll
    for (int q = 0; q < NBMAX; q++) cur[q] = wbase[w][q] + pre[q];

    // pass 2: place (one store per edge; cndmask select chain for the cursor)
#pragma unroll
    for (int it = 0; it < EPT / 4; it++) {
        int idx = base + it * 1024 + t * 4;
        if (idx + 3 < E) {
            int4 sv = *(const int4*)(ei + idx);
            int4 dv = *(const int4*)(ei + (size_t)E + idx);
            int dd[4] = {dv.x, dv.y, dv.z, dv.w};
            int ss[4] = {sv.x, sv.y, sv.z, sv.w};
#pragma unroll
            for (int e = 0; e < 4; e++) {
                int bq = dd[e] >> BSHIFT;
                int pk = ((dd[e] & (BRANGE - 1)) << 17) | ss[e];
                int off = cur[0];
#pragma unroll
                for (int q = 1; q < NBMAX; q++) off = (bq == q) ? cur[q] : off;
                if (off < CAP) bkt[(size_t)bq * CAP + off] = pk;
#pragma unroll
                for (int q = 0; q < NBMAX; q++) cur[q] += (bq == q);
            }
        } else {
            for (int k = idx; k < E && k < idx + 4; k++) {
                int d = ei[(size_t)E + k], s = ei[k];
                int bq = d >> BSHIFT;
                int pk = ((d & (BRANGE - 1)) << 17) | s;
                int off = cur[0];
#pragma unroll
                for (int q = 1; q < NBMAX; q++) off = (bq == q) ? cur[q] : off;
                if (off < CAP) bkt[(size_t)bq * CAP + off] = pk;
#pragma unroll
                for (int q = 0; q < NBMAX; q++) cur[q] += (bq == q);
            }
        }
    }
}

__device__ __forceinline__ void wprep_part(
    int b2, int t, const float* __restrict__ W1, const float* __restrict__ as1,
    const float* __restrict__ ad1, const float* __restrict__ W2,
    const float* __restrict__ as2, const float* __restrict__ ad2,
    ushortT* __restrict__ wf1_hi, ushortT* __restrict__ wf1_lo,
    ushortT* __restrict__ wf2_hi, ushortT* __restrict__ wf2_lo) {
    const float *W, *att_s, *att_d;
    ushortT *whi, *wlo;
    int idx;
    if (b2 < 9) {
        W = W1; att_s = as1; att_d = ad1; whi = wf1_hi; wlo = wf1_lo;
        idx = b2 * 256 + t;
    } else {
        W = W2; att_s = as2; att_d = ad2; whi = wf2_hi; wlo = wf2_lo;
        idx = (b2 - 9) * 256 + t;
    }
    if (idx >= 4 * 9 * 64) return;
    int lane = idx & 63;
    int nt = (idx >> 6) % 9;
    int kt = idx / (9 * 64);
    int quad = lane >> 4, ncol = lane & 15;
#pragma unroll
    for (int j = 0; j < 8; j++) {
        int k = kt * 32 + quad * 8 + j;
        float v;
        if (nt < 8) {
            v = W[k * D + nt * 16 + ncol];
        } else {
            const float* att = (ncol < 8) ? att_s : att_d;
            int hd = ncol & 7;
            float s = 0.f;
            for (int c = 0; c < 16; c++)
                s += W[k * D + hd * 16 + c] * att[hd * 16 + c];
            v = s;
        }
        unsigned short hi = f2bf(v);
        unsigned short lo = f2bf(v - bf2f(hi));
        whi[idx * 8 + j] = hi;
        wlo[idx * 8 + j] = lo;
    }
}

__device__ __forceinline__ void xsplit_part(
    int idx, const float* __restrict__ x, ushortT* __restrict__ xh,
    ushortT* __restrict__ xl, int n, int nt16) {
    int r = idx >> 4;
    if (r >= nt16 * 16) return;
    int kb = idx & 15;
    float4 v0 = make_float4(0.f, 0.f, 0.f, 0.f), v1 = v0;
    if (r < n) {
        v0 = ((const float4*)(x + (size_t)r * D + kb * 8))[0];
        v1 = ((const float4*)(x + (size_t)r * D + kb * 8))[1];
    }
    int wt = r >> 4, m = r & 15, kt = kb >> 2, quad = kb & 3;
    int base = ((wt * 4 + kt) * 64 + (m + 16 * quad)) * 8;
    ushort4 h0, l0, h1, l1;
    h0.x = f2bf(v0.x); l0.x = f2bf(v0.x - bf2f(h0.x));
    h0.y = f2bf(v0.y); l0.y = f2bf(v0.y - bf2f(h0.y));
    h0.z = f2bf(v0.z); l0.z = f2bf(v0.z - bf2f(h0.z));
    h0.w = f2bf(v0.w); l0.w = f2bf(v0.w - bf2f(h0.w));
    h1.x = f2bf(v1.x); l1.x = f2bf(v1.x - bf2f(h1.x));
    h1.y = f2bf(v1.y); l1.y = f2bf(v1.y - bf2f(h1.y));
    h1.z = f2bf(v1.z); l1.z = f2bf(v1.z - bf2f(h1.z));
    h1.w = f2bf(v1.w); l1.w = f2bf(v1.w - bf2f(h1.w));
    *(ushort4*)(xh + base) = h0;
    *(ushort4*)(xh + base + 4) = h1;
    *(ushort4*)(xl + base) = l0;
    *(ushort4*)(xl + base + 4) = l1;
}

__global__ __launch_bounds__(256) void k_prep(
    const int* __restrict__ ei, int* __restrict__ bkt, int* __restrict__ bcur,
    int E, const float* __restrict__ x, ushortT* __restrict__ xh,
    ushortT* __restrict__ xl, int n, int nt16,
    const float* __restrict__ W1, const float* __restrict__ as1,
    const float* __restrict__ ad1, const float* __restrict__ W2,
    const float* __restrict__ as2, const float* __restrict__ ad2,
    ushortT* __restrict__ wf1_hi, ushortT* __restrict__ wf1_lo,
    ushortT* __restrict__ wf2_hi, ushortT* __restrict__ wf2_lo, int nbb) {
    int b = blockIdx.x;
    int t = threadIdx.x;
    if (b < nbb) {
        bucket_part(b, t, ei, bkt, bcur, E);
    } else if (b < nbb + 18) {
        wprep_part(b - nbb, t, W1, as1, ad1, W2, as2, ad2,
                   wf1_hi, wf1_lo, wf2_hi, wf2_lo);
    } else {
        xsplit_part((b - nbb - 18) * 256 + t, x, xh, xl, n, nt16);
    }
}

// ---------------- per-(bucket,segment) LDS histogram -> hseg (no atomics) -------

__global__ __launch_bounds__(256) void k_count(
    const int* __restrict__ bkt, const int* __restrict__ bcur,
    int* __restrict__ hseg, int n) {
    __shared__ int lcnt[BRANGE];
    int t = threadIdx.x;
    int q = blockIdx.x >> 4, s = blockIdx.x & (NSEG - 1);
    for (int i = t; i < BRANGE; i += 256) lcnt[i] = 0;
    __syncthreads();
    int tot = bcur[q * 16];
    if (tot > CAP) tot = CAP;
    int per = ((tot + NSEG - 1) / NSEG + 3) & ~3;   // 4-aligned split
    int lo = s * per;
    int hi = lo + per; if (hi > tot) hi = tot;
    const int* bp = bkt + (size_t)q * CAP;
    for (int i = lo + t * 4; i < hi; i += 1024) {
        if (i + 3 < hi) {
            int4 v = *(const int4*)(bp + i);
            atomicAdd(&lcnt[v.x >> 17], 1);
            atomicAdd(&lcnt[v.y >> 17], 1);
            atomicAdd(&lcnt[v.z >> 17], 1);
            atomicAdd(&lcnt[v.w >> 17], 1);
        } else {
            for (int k = i; k < hi; k++) atomicAdd(&lcnt[bp[k] >> 17], 1);
        }
    }
    __syncthreads();
    int* hp = hseg + ((size_t)(q * NSEG + s) << BSHIFT);
    for (int i = t; i < BRANGE; i += 256) hp[i] = lcnt[i];
}

// ---------------- single-pass decoupled-lookback scan + self-loop/pads ----------
// <=64 blocks, all co-resident on 256 CUs -> spin-free-deadlock guaranteed.
// Node counts = sum of the NSEG segment histograms (registers). After poffs is
// known, hseg is overwritten IN PLACE with per-segment exclusive bases:
// sbase[q][s][node] = poffs[node] + sum_{s'<s} hseg[q][s'][node]. Refine blocks
// then own disjoint slot ranges with zero cross-block coordination.

__global__ __launch_bounds__(256) void k_scan_lb(
    int* __restrict__ hseg, int* __restrict__ poffs,
    int* __restrict__ sstate, int* __restrict__ csrsrc, int n) {
    __shared__ int lds[256];
    __shared__ int bprefix;
    int t = threadIdx.x;
    int b = blockIdx.x;
    int base = b * SCAN_TILE + t * 4;      // SCAN_TILE divides BRANGE ->
    int q = base >> BSHIFT;                // all 4 nodes in one bucket
    int li = base & (BRANGE - 1);
    int4 hv[NSEG];
    int c[4] = {0, 0, 0, 0};
    bool any = (base < n);
    if (any) {
#pragma unroll
        for (int s = 0; s < NSEG; s++) {
            hv[s] = *(const int4*)(hseg + ((size_t)(q * NSEG + s) << BSHIFT) + li);
            c[0] += hv[s].x; c[1] += hv[s].y; c[2] += hv[s].z; c[3] += hv[s].w;
        }
    }
    int ssum = padc(c[0]) + padc(c[1]) + padc(c[2]) + padc(c[3]);
    lds[t] = ssum;
    __syncthreads();
    for (int st = 1; st < 256; st <<= 1) {
        int add = (t >= st) ? lds[t - st] : 0;
        __syncthreads();
        lds[t] += add;
        __syncthreads();
    }
    if (t == 0)
        __hip_atomic_store(&sstate[b], lds[255] | (1 << 30),
                           __ATOMIC_RELEASE, __HIP_MEMORY_SCOPE_AGENT);
    if (t < 64) {
        int v = 0;
        if (t < b) {
            int x;
            do {
                x = __hip_atomic_load(&sstate[t], __ATOMIC_RELAXED,
                                      __HIP_MEMORY_SCOPE_AGENT);
            } while (!(x & (1 << 30)));
            v = x & 0x3FFFFFFF;
        }
#pragma unroll
        for (int o = 32; o > 0; o >>= 1) v += __shfl_down(v, o);
        if (t == 0) bprefix = v;
    }
    __syncthreads();
    int run = bprefix + ((t == 0) ? 0 : lds[t - 1]);
    if (b == 0 && t == 0) poffs[0] = 0;
    int runk[4];
#pragma unroll
    for (int k = 0; k < 4; k++) {
        int i = base + k;
        runk[k] = run;
        if (i < n) {
            int pv = padc(c[k]);
            csrsrc[run + c[k]] = i;                        // self-loop last
            for (int k2 = c[k] + 1; k2 < pv; k2++)
                csrsrc[run + k2] = n;                      // sentinel pads
            run += pv;
            poffs[i + 1] = run;
        }
    }
    if (any) {
        int a0 = runk[0], a1 = runk[1], a2 = runk[2], a3 = runk[3];
#pragma unroll
        for (int s = 0; s < NSEG; s++) {
            int4 v = hv[s];
            int4 w; w.x = a0; w.y = a1; w.z = a2; w.w = a3;
            *(int4*)(hseg + ((size_t)(q * NSEG + s) << BSHIFT) + li) = w;
            a0 += v.x; a1 += v.y; a2 += v.z; a3 += v.w;
        }
    }
}

// ---------------- gemm wave body (split-bf16 MFMA, LDS-free) ----------------

__device__ __forceinline__ void gemm_wave(
    int wt, int lane, const ushortT* __restrict__ xh,
    const ushortT* __restrict__ xl, const ushortT* __restrict__ wf_hi,
    const ushortT* __restrict__ wf_lo, ushortT* __restrict__ hout,
    float* __restrict__ as_, float* __restrict__ ad_, int n) {
    f32x4 acc[9];
#pragma unroll
    for (int nt = 0; nt < 9; nt++) acc[nt] = (f32x4){0.f, 0.f, 0.f, 0.f};

#pragma unroll
    for (int kt = 0; kt < 4; kt++) {
        short8 a_hi = *(const short8*)(xh + (size_t)((wt * 4 + kt) * 64 + lane) * 8);
        short8 a_lo = *(const short8*)(xl + (size_t)((wt * 4 + kt) * 64 + lane) * 8);
        const ushortT* bh = wf_hi + (size_t)(kt * 576 + lane) * 8;
        const ushortT* bl = wf_lo + (size_t)(kt * 576 + lane) * 8;
#pragma unroll
        for (int nt = 0; nt < 9; nt++) {
            short8 b_hi = *(const short8*)(bh + nt * 512);
            short8 b_lo = *(const short8*)(bl + nt * 512);
            acc[nt] = __builtin_amdgcn_mfma_f32_16x16x32_bf16(a_hi, b_hi, acc[nt], 0, 0, 0);
            acc[nt] = __builtin_amdgcn_mfma_f32_16x16x32_bf16(a_lo, b_hi, acc[nt], 0, 0, 0);
            acc[nt] = __builtin_amdgcn_mfma_f32_16x16x32_bf16(a_hi, b_lo, acc[nt], 0, 0, 0);
        }
    }

    // C/D layout: col = lane&15, row = (lane>>4)*4 + reg (m89-verified)
    int q = lane >> 4, ncol = lane & 15;
    int rbase = wt * 16 + q * 4;
#pragma unroll
    for (int nt = 0; nt < 8; nt++) {
#pragma unroll
        for (int reg = 0; reg < 4; reg++) {
            int r = rbase + reg;
            if (r < n) hout[(size_t)r * D + nt * 16 + ncol] = f2bf(acc[nt][reg]);
        }
    }
#pragma unroll
    for (int reg = 0; reg < 4; reg++) {
        int r = rbase + reg;
        if (r < n) {
            float v = acc[8][reg];
            if (ncol < 8) as_[r * H + ncol] = v;
            else          ad_[r * H + (ncol - 8)] = v;
        }
    }
}

// ---------------- fused: CSR refine (segment-parallel) | layer-1 gemm -----------
// Refine block (q,s): seed LDS cursors from the in-place sbase slice of hseg,
// then per edge LDS returning atomicAdd -> unique global slot -> csrsrc store.
// nbkt*NSEG refine blocks overlap the gemm blocks; no global returning atomics.

__global__ __launch_bounds__(256) void k_fillgemm(
    const int* __restrict__ poffs, const int* __restrict__ bkt,
    const int* __restrict__ bcur, const int* __restrict__ hseg,
    int* __restrict__ csrsrc,
    ushortT* __restrict__ hbuf_s, float* __restrict__ asrc_s,
    const ushortT* __restrict__ xh, const ushortT* __restrict__ xl,
    const ushortT* __restrict__ wf_hi, const ushortT* __restrict__ wf_lo,
    ushortT* __restrict__ hout, float* __restrict__ as_,
    float* __restrict__ ad_, int n, int gb, int nrb) {
    int b = blockIdx.x;
    int t = threadIdx.x;
    if (b < gb) {
        int wt = b * 4 + (t >> 6);
        if (wt * 16 < n)
            gemm_wave(wt, t & 63, xh, xl, wf_hi, wf_lo, hout, as_, ad_, n);
        return;
    }
    int rb = b - gb;
    if (rb < nrb) {
        __shared__ int cur[BRANGE];
        int q = rb >> 4, s = rb & (NSEG - 1);
        const int* sp = hseg + ((size_t)(q * NSEG + s) << BSHIFT);
        for (int i = t; i < BRANGE; i += 256) cur[i] = sp[i];
        __syncthreads();
        int tot = bcur[q * 16];
        if (tot > CAP) tot = CAP;
        int per = ((tot + NSEG - 1) / NSEG + 3) & ~3;
        int lo = s * per;
        int hi = lo + per; if (hi > tot) hi = tot;
        const int* bp = bkt + (size_t)q * CAP;
        for (int i = lo + t * 4; i < hi; i += 1024) {
            if (i + 3 < hi) {
                int4 v = *(const int4*)(bp + i);
                int s0 = atomicAdd(&cur[v.x >> 17], 1);
                int s1 = atomicAdd(&cur[v.y >> 17], 1);
                int s2 = atomicAdd(&cur[v.z >> 17], 1);
                int s3 = atomicAdd(&cur[v.w >> 17], 1);
                csrsrc[s0] = v.x & 0x1FFFF;
                csrsrc[s1] = v.y & 0x1FFFF;
                csrsrc[s2] = v.z & 0x1FFFF;
                csrsrc[s3] = v.w & 0x1FFFF;
            } else {
                for (int k = i; k < hi; k++) {
                    int v = bp[k];
                    int sl = atomicAdd(&cur[v >> 17], 1);
                    csrsrc[sl] = v & 0x1FFFF;
                }
            }
        }
        return;
    }
    if (rb == nrb && t == 0) {
        int total = poffs[n];
        for (int k = 0; k < 8; k++) csrsrc[total + k] = n;        // slack
        for (int k = 0; k < D; k++) hbuf_s[(size_t)n * D + k] = 0; // sentinel row
        for (int h = 0; h < H; h++) asrc_s[n * H + h] = -1e30f;    // weight -> 0
    }
}

// ---------------- standalone gemm (layer 2) ----------------

__global__ __launch_bounds__(256) void k_gemm_att(
    const ushortT* __restrict__ xh, const ushortT* __restrict__ xl,
    const ushortT* __restrict__ wf_hi, const ushortT* __restrict__ wf_lo,
    ushortT* __restrict__ hout, float* __restrict__ as_,
    float* __restrict__ ad_, int n) {
    int t = threadIdx.x;
    int wt = blockIdx.x * 4 + (t >> 6);
    if (wt * 16 >= n) return;
    gemm_wave(wt, t & 63, xh, xl, wf_hi, wf_lo, hout, as_, ad_, n);
}

// ---------------- aggregate: 2 nodes/wave, 8-edge unroll, dword cvt -------------
// Lanes 0-31 = node A, 32-63 = node B; lane ll owns channels ll*4..+3.
// 8 gathers in flight per lane; bf16->f32 via dword shift/mask; f32x4 vector
// accumulate (v_pk_fma_f32 eligible). out_mode 0: f32 final output.
// out_mode 1: relu, then bf16 hi/lo split written in A-frag order.

__global__ __launch_bounds__(256) void k_aggregate(
    const ushortT* __restrict__ hbuf, const float* __restrict__ asrc,
    const float* __restrict__ adst, const int* __restrict__ csr,
    const int* __restrict__ poffs, const float* __restrict__ bias,
    float* __restrict__ out, ushortT* __restrict__ oh, ushortT* __restrict__ ol,
    int out_mode, int n) {
    int t = threadIdx.x;
    int d = blockIdx.x * 8 + (t >> 5);
    if (d >= n) return;
    int ll = t & 31;
    int h = ll >> 2;
    int llo = ll * 2;                       // dword offset within row
    const unsigned int* hb = (const unsigned int*)hbuf;  // row = 64 dwords

    int off = poffs[d];
    int degp = poffs[d + 1] - off;   // multiple of 4, >= 4
    float adh = adst[d * H + h];
    const int* cp = csr + off;

    f32x4 acc = {0.f, 0.f, 0.f, 0.f};
    float ssum = 0.f;

    int j = 0;
    for (; j + 8 <= degp; j += 8) {
        int4 sa = *(const int4*)(cp + j);
        int4 sb = *(const int4*)(cp + j + 4);
        int s_[8] = {sa.x, sa.y, sa.z, sa.w, sb.x, sb.y, sb.z, sb.w};
        float e_[8];
        uint2 u_[8];
#pragma unroll
        for (int k = 0; k < 8; k++) {
            e_[k] = asrc[s_[k] * H + h];
            u_[k] = *(const uint2*)(hb + s_[k] * 64 + llo);
        }
#pragma unroll
        for (int k = 0; k < 8; k++) {
            float e = e_[k] + adh;
            float w = __expf(fmaxf(e, NEG_SLOPE * e));
            ssum += w;
            f32x4 hv;
            hv.x = __uint_as_float(u_[k].x << 16);
            hv.y = __uint_as_float(u_[k].x & 0xffff0000u);
            hv.z = __uint_as_float(u_[k].y << 16);
            hv.w = __uint_as_float(u_[k].y & 0xffff0000u);
            acc += hv * w;
        }
    }
    if (j < degp) {                         // 4-edge tail (degp % 8 == 4)
        int4 sa = *(const int4*)(cp + j);
        int s_[4] = {sa.x, sa.y, sa.z, sa.w};
        float e_[4];
        uint2 u_[4];
#pragma unroll
        for (int k = 0; k < 4; k++) {
            e_[k] = asrc[s_[k] * H + h];
            u_[k] = *(const uint2*)(hb + s_[k] * 64 + llo);
        }
#pragma unroll
        for (int k = 0; k < 4; k++) {
            float e = e_[k] + adh;
            float w = __expf(fmaxf(e, NEG_SLOPE * e));
            ssum += w;
            f32x4 hv;
            hv.x = __uint_as_float(u_[k].x << 16);
            hv.y = __uint_as_float(u_[k].x & 0xffff0000u);
            hv.z = __uint_as_float(u_[k].y << 16);
            hv.w = __uint_as_float(u_[k].y & 0xffff0000u);
            acc += hv * w;
        }
    }

    float inv = 1.f / ssum;
    float4 b = ((const float4*)bias)[ll];
    float4 r;
    r.x = acc.x * inv + b.x;
    r.y = acc.y * inv + b.y;
    r.z = acc.z * inv + b.z;
    r.w = acc.w * inv + b.w;

    if (out_mode == 0) {
        ((float4*)(out + (size_t)d * D))[ll] = r;
    } else {
        r.x = fmaxf(r.x, 0.f);
        r.y = fmaxf(r.y, 0.f);
        r.z = fmaxf(r.z, 0.f);
        r.w = fmaxf(r.w, 0.f);
        // A-frag address for (row d, cols ll*4..+3)
        int wt = d >> 4, m = d & 15;
        int kt = ll >> 3, quad = (ll >> 1) & 3, j0 = (ll & 1) * 4;
        int base = ((wt * 4 + kt) * 64 + (m + 16 * quad)) * 8 + j0;
        ushort4 hv, lv;
        hv.x = f2bf(r.x); lv.x = f2bf(r.x - bf2f(hv.x));
        hv.y = f2bf(r.y); lv.y = f2bf(r.y - bf2f(hv.y));
        hv.z = f2bf(r.z); lv.z = f2bf(r.z - bf2f(hv.z));
        hv.w = f2bf(r.w); lv.w = f2bf(r.w - bf2f(hv.w));
        *(ushort4*)(oh + base) = hv;
        *(ushort4*)(ol + base) = lv;
    }
}

// ---------------- launch ----------------

extern "C" void kernel_launch(void* const* d_in, const int* in_sizes, int n_in,
                              void* d_out, int out_size, void* d_ws, size_t ws_size,
                              hipStream_t stream) {
    const float* x   = (const float*)d_in[0];
    const int*   ei  = (const int*)d_in[1];
    const float* W1  = (const float*)d_in[2];
    const float* as1 = (const float*)d_in[3];
    const float* ad1 = (const float*)d_in[4];
    const float* b1  = (const float*)d_in[5];
    const float* W2  = (const float*)d_in[6];
    const float* as2 = (const float*)d_in[7];
    const float* ad2 = (const float*)d_in[8];
    const float* b2  = (const float*)d_in[9];
    float* out = (float*)d_out;

    int N = in_sizes[0] / D;
    int E = in_sizes[1] / 2;
    int NT16 = (N + 15) / 16;
    int nb_scan = (N + SCAN_TILE - 1) / SCAN_TILE;   // <= 64 assumed (N <= 64K)
    int nbkt = (N + BRANGE - 1) >> BSHIFT;           // <= 16 assumed
    int nrb = nbkt * NSEG;                           // refine/count blocks
    const int WFN = 4 * 9 * 64 * 8;  // 18432 ushorts per wf buffer
    size_t XS = (size_t)NT16 * 2048; // ushorts per split buffer

    // workspace layout; sentinel row n in hbuf/asrc
    ushortT* hbuf = (ushortT*)d_ws;                        // (N+1)*D bf16
    ushortT* xsh  = hbuf + (size_t)(N + 1) * D;            // split hi (frag order)
    ushortT* xsl  = xsh + XS;                              // split lo
    float* asrc = (float*)(xsl + XS);                      // (N+1)*H
    float* adst = asrc + (size_t)(N + 1) * H;              // N*H
    int*   poffs  = (int*)(adst + (size_t)N * H);          // N+1
    int*   sstate = poffs + ((N + 1 + 3) & ~3);            // 64 (lookback state)
    int*   bcur   = sstate + 64;                           // 16*16 bucket cursors
    int*   csrsrc = bcur + 256;                            // E + 4N + 8
    int*   bkt    = csrsrc + ((E + 4 * N + 8 + 3) & ~3);   // nbkt*CAP packed edges
    int*   hseg   = bkt + (size_t)nbkt * CAP;              // nrb*BRANGE seg hists
    ushortT* wf1_hi = (ushortT*)(hseg + (size_t)nrb * BRANGE);
    ushortT* wf1_lo = wf1_hi + WFN;
    ushortT* wf2_hi = wf1_lo + WFN;
    ushortT* wf2_lo = wf2_hi + WFN;

    // zero lookback state + bucket cursors (hseg fully written by k_count)
    hipMemsetAsync(sstate, 0, 320 * sizeof(int), stream);

    int nbb = (E + BEDGES - 1) / BEDGES;
    int nbx = (NT16 * 16 * 16 + 255) / 256;  // xsplit: 16 threads/row
    k_prep<<<nbb + 18 + nbx, 256, 0, stream>>>(
        ei, bkt, bcur, E, x, xsh, xsl, N, NT16,
        W1, as1, ad1, W2, as2, ad2, wf1_hi, wf1_lo, wf2_hi, wf2_lo, nbb);

    k_count<<<nrb, 256, 0, stream>>>(bkt, bcur, hseg, N);

    k_scan_lb<<<nb_scan, 256, 0, stream>>>(hseg, poffs, sstate, csrsrc, N);

    int gb = (NT16 + 3) / 4;
    int ab = (N + 7) / 8;
    // layer 1: CSR refine | gemm fused
    k_fillgemm<<<gb + nrb + 1, 256, 0, stream>>>(
        poffs, bkt, bcur, hseg, csrsrc, hbuf, asrc,
        xsh, xsl, wf1_hi, wf1_lo, hbuf, asrc, adst, N, gb, nrb);
    k_aggregate<<<ab, 256, 0, stream>>>(hbuf, asrc, adst, csrsrc, poffs, b1,
                                        out, xsh, xsl, 1, N);
    // layer 2 (reads split frags produced by aggregate 1)
    k_gemm_att<<<gb, 256, 0, stream>>>(xsh, xsl, wf2_hi, wf2_lo, hbuf, asrc, adst, N);
    k_aggregate<<<ab, 256, 0, stream>>>(hbuf, asrc, adst, csrsrc, poffs, b2,
                                        out, xsh, xsl, 0, N);
}